// Round 1
// baseline (221.000 us; speedup 1.0000x reference)
//
#include <hip/hip_runtime.h>
#include <math.h>

// Problem constants
#define NB 4      // batch
#define NC 64     // channels
#define NI 16     // inter-channels
#define NH 128    // height
#define NW 128    // width
#define ND 64     // downsampled h/w
#define NN 4096   // ND*ND pixels
#define MS 16     // m-splits in attention
#define MC 256    // NN/MS columns per split

#define SEG (NB*NN*NI)  // 262144 floats

// ---------------------------------------------------------------------------
// Kernel 1: fused downsample (point-sample at odd pixels, per jax
// scale_and_translate with translation=0.5*(s-1)) + theta/phi/g projections.
// Output layouts all [b][n][16] (phi stored transposed vs reference's [b,16,n]).
// ---------------------------------------------------------------------------
extern "C" __global__ __launch_bounds__(256)
void k_proj(const float* __restrict__ x,
            const float* __restrict__ gw, const float* __restrict__ gb,
            const float* __restrict__ tw, const float* __restrict__ tb,
            const float* __restrict__ pw, const float* __restrict__ pb,
            float* __restrict__ th, float* __restrict__ ph, float* __restrict__ g)
{
    __shared__ float swt[NC][48];  // [c][0:16)=theta [16:32)=phi [32:48)=g
    __shared__ float sb[48];
    int tid = threadIdx.x;
    for (int idx = tid; idx < NI*NC; idx += 256) {
        int o = idx >> 6, c = idx & 63;
        swt[c][o]      = tw[idx];
        swt[c][16 + o] = pw[idx];
        swt[c][32 + o] = gw[idx];
    }
    if (tid < 16) { sb[tid] = tb[tid]; sb[16+tid] = pb[tid]; sb[32+tid] = gb[tid]; }
    __syncthreads();

    int bq = blockIdx.x * 256 + tid;   // 0..16383
    int b = bq >> 12, q = bq & 4095;
    int i = q >> 6, j = q & 63;
    const float* xp = x + (((size_t)(b*NC)*NH + (2*i+1))*NW + (2*j+1));
    float aT[16], aP[16], aG[16];
#pragma unroll
    for (int o = 0; o < 16; ++o) { aT[o] = 0.f; aP[o] = 0.f; aG[o] = 0.f; }
    for (int c = 0; c < NC; ++c) {
        float xd = xp[(size_t)c*NH*NW];
        const float* wr = swt[c];
#pragma unroll
        for (int o = 0; o < 16; ++o) aT[o] += xd*wr[o];
#pragma unroll
        for (int o = 0; o < 16; ++o) aP[o] += xd*wr[16+o];
#pragma unroll
        for (int o = 0; o < 16; ++o) aG[o] += xd*wr[32+o];
    }
    float4* tp = (float4*)(th + (size_t)bq*16);
    float4* pp = (float4*)(ph + (size_t)bq*16);
    float4* gp = (float4*)(g  + (size_t)bq*16);
#pragma unroll
    for (int k = 0; k < 4; ++k) {
        tp[k] = make_float4(aT[4*k]+sb[4*k],   aT[4*k+1]+sb[4*k+1],
                            aT[4*k+2]+sb[4*k+2], aT[4*k+3]+sb[4*k+3]);
        pp[k] = make_float4(aP[4*k]+sb[16+4*k],   aP[4*k+1]+sb[16+4*k+1],
                            aP[4*k+2]+sb[16+4*k+2], aP[4*k+3]+sb[16+4*k+3]);
        gp[k] = make_float4(aG[4*k]+sb[32+4*k],   aG[4*k+1]+sb[32+4*k+1],
                            aG[4*k+2]+sb[32+4*k+2], aG[4*k+3]+sb[32+4*k+3]);
    }
}

// ---------------------------------------------------------------------------
// Kernel 2: flash attention, max-free softmax (scores ~N(0,1), no overflow),
// split over m into MS chunks. Each block: 512 queries (2/thread), one m-chunk
// of 256 columns staged in LDS (broadcast reads: wave-uniform address).
// Partials: accp[ms][b][q][16], lp[ms][b][q].
// ---------------------------------------------------------------------------
extern "C" __global__ __launch_bounds__(256)
void k_attn(const float* __restrict__ th, const float* __restrict__ ph,
            const float* __restrict__ g, float* __restrict__ accp,
            float* __restrict__ lp)
{
    __shared__ float4 sph[MC*4];  // 16 KB
    __shared__ float4 sg[MC*4];   // 16 KB
    int tid = threadIdx.x;
    int qb = blockIdx.x, ms = blockIdx.y, b = blockIdx.z;
    const float4* phs = (const float4*)(ph + ((size_t)b*NN + ms*MC)*16);
    const float4* gs  = (const float4*)(g  + ((size_t)b*NN + ms*MC)*16);
    for (int idx = tid; idx < MC*4; idx += 256) { sph[idx] = phs[idx]; sg[idx] = gs[idx]; }
    __syncthreads();

    int q0 = qb*512 + tid;
    int q1 = q0 + 256;
    const float4* t0 = (const float4*)(th + ((size_t)b*NN + q0)*16);
    const float4* t1 = (const float4*)(th + ((size_t)b*NN + q1)*16);
    float4 A0 = t0[0], A1 = t0[1], A2 = t0[2], A3 = t0[3];
    float4 B0 = t1[0], B1 = t1[1], B2 = t1[2], B3 = t1[3];
    float acc0[16], acc1[16];
#pragma unroll
    for (int k = 0; k < 16; ++k) { acc0[k] = 0.f; acc1[k] = 0.f; }
    float l0 = 0.f, l1 = 0.f;

    for (int m = 0; m < MC; ++m) {
        float4 p0 = sph[4*m], p1 = sph[4*m+1], p2 = sph[4*m+2], p3 = sph[4*m+3];
        float s0 = A0.x*p0.x + A0.y*p0.y + A0.z*p0.z + A0.w*p0.w
                 + A1.x*p1.x + A1.y*p1.y + A1.z*p1.z + A1.w*p1.w
                 + A2.x*p2.x + A2.y*p2.y + A2.z*p2.z + A2.w*p2.w
                 + A3.x*p3.x + A3.y*p3.y + A3.z*p3.z + A3.w*p3.w;
        float s1 = B0.x*p0.x + B0.y*p0.y + B0.z*p0.z + B0.w*p0.w
                 + B1.x*p1.x + B1.y*p1.y + B1.z*p1.z + B1.w*p1.w
                 + B2.x*p2.x + B2.y*p2.y + B2.z*p2.z + B2.w*p2.w
                 + B3.x*p3.x + B3.y*p3.y + B3.z*p3.z + B3.w*p3.w;
        float e0 = __expf(s0), e1 = __expf(s1);
        l0 += e0; l1 += e1;
        float4 g0 = sg[4*m], g1 = sg[4*m+1], g2 = sg[4*m+2], g3 = sg[4*m+3];
        acc0[0]  += e0*g0.x; acc0[1]  += e0*g0.y; acc0[2]  += e0*g0.z; acc0[3]  += e0*g0.w;
        acc0[4]  += e0*g1.x; acc0[5]  += e0*g1.y; acc0[6]  += e0*g1.z; acc0[7]  += e0*g1.w;
        acc0[8]  += e0*g2.x; acc0[9]  += e0*g2.y; acc0[10] += e0*g2.z; acc0[11] += e0*g2.w;
        acc0[12] += e0*g3.x; acc0[13] += e0*g3.y; acc0[14] += e0*g3.z; acc0[15] += e0*g3.w;
        acc1[0]  += e1*g0.x; acc1[1]  += e1*g0.y; acc1[2]  += e1*g0.z; acc1[3]  += e1*g0.w;
        acc1[4]  += e1*g1.x; acc1[5]  += e1*g1.y; acc1[6]  += e1*g1.z; acc1[7]  += e1*g1.w;
        acc1[8]  += e1*g2.x; acc1[9]  += e1*g2.y; acc1[10] += e1*g2.z; acc1[11] += e1*g2.w;
        acc1[12] += e1*g3.x; acc1[13] += e1*g3.y; acc1[14] += e1*g3.z; acc1[15] += e1*g3.w;
    }

    size_t base0 = (((size_t)ms*NB + b)*NN + q0)*4;  // float4 units
    size_t base1 = (((size_t)ms*NB + b)*NN + q1)*4;
    float4* ap = (float4*)accp;
#pragma unroll
    for (int k = 0; k < 4; ++k) {
        ap[base0+k] = make_float4(acc0[4*k], acc0[4*k+1], acc0[4*k+2], acc0[4*k+3]);
        ap[base1+k] = make_float4(acc1[4*k], acc1[4*k+1], acc1[4*k+2], acc1[4*k+3]);
    }
    lp[((size_t)ms*NB + b)*NN + q0] = l0;
    lp[((size_t)ms*NB + b)*NN + q1] = l1;
}

// ---------------------------------------------------------------------------
// Kernel 3: combine partials (pure sums, max-free) and store y transposed:
// yt[b][i][n]  (n = ih*64+iw), i.e. [b,16,64,64].
// ---------------------------------------------------------------------------
extern "C" __global__ __launch_bounds__(256)
void k_combine(const float* __restrict__ accp, const float* __restrict__ lp,
               float* __restrict__ yt)
{
    int bq = blockIdx.x*256 + threadIdx.x;
    int b = bq >> 12, q = bq & 4095;
    float acc[16];
#pragma unroll
    for (int k = 0; k < 16; ++k) acc[k] = 0.f;
    float l = 0.f;
    for (int ms = 0; ms < MS; ++ms) {
        const float4* ap = (const float4*)accp + (((size_t)ms*NB + b)*NN + q)*4;
        float4 v0 = ap[0], v1 = ap[1], v2 = ap[2], v3 = ap[3];
        acc[0]+=v0.x;  acc[1]+=v0.y;  acc[2]+=v0.z;  acc[3]+=v0.w;
        acc[4]+=v1.x;  acc[5]+=v1.y;  acc[6]+=v1.z;  acc[7]+=v1.w;
        acc[8]+=v2.x;  acc[9]+=v2.y;  acc[10]+=v2.z; acc[11]+=v2.w;
        acc[12]+=v3.x; acc[13]+=v3.y; acc[14]+=v3.z; acc[15]+=v3.w;
        l += lp[((size_t)ms*NB + b)*NN + q];
    }
    float inv = 1.f / l;
#pragma unroll
    for (int i = 0; i < 16; ++i)
        yt[((size_t)b*NI + i)*NN + q] = acc[i]*inv;
}

// ---------------------------------------------------------------------------
// Kernel 4: bilinear upsample (sample = o/2 - 0.5: odd o copies, even o
// averages neighbors; edge renorm == clamp) + out-projection + residual:
// z = x + out_w . yup + out_b. One block per (b,h) row, 128 threads = w.
// ---------------------------------------------------------------------------
extern "C" __global__ __launch_bounds__(128)
void k_out(const float* __restrict__ yt, const float* __restrict__ x,
           const float* __restrict__ ow, const float* __restrict__ ob,
           float* __restrict__ z)
{
    __shared__ float syup[NI][NW];  // 8 KB
    __shared__ float sw[NC*NI];     // 4 KB
    __shared__ float sbv[NC];
    int w = threadIdx.x, h = blockIdx.x, b = blockIdx.y;
    for (int idx = w; idx < NC*NI; idx += 128) sw[idx] = ow[idx];
    if (w < NC) sbv[w] = ob[w];

    float chf = h*0.5f - 0.5f;
    int h0 = (int)floorf(chf); float fh = chf - (float)h0;
    int h1 = h0 + 1; if (h1 > ND-1) h1 = ND-1; if (h0 < 0) h0 = 0;
    float cwf = w*0.5f - 0.5f;
    int w0 = (int)floorf(cwf); float fw = cwf - (float)w0;
    int w1 = w0 + 1; if (w1 > ND-1) w1 = ND-1; if (w0 < 0) w0 = 0;
    float w00=(1.f-fh)*(1.f-fw), w01=(1.f-fh)*fw, w10=fh*(1.f-fw), w11=fh*fw;
    for (int i = 0; i < NI; ++i) {
        const float* yp = yt + ((size_t)b*NI + i)*NN;
        syup[i][w] = w00*yp[h0*ND+w0] + w01*yp[h0*ND+w1]
                   + w10*yp[h1*ND+w0] + w11*yp[h1*ND+w1];
    }
    __syncthreads();

    float yv[16];
#pragma unroll
    for (int i = 0; i < 16; ++i) yv[i] = syup[i][w];
    for (int c = 0; c < NC; ++c) {
        const float* wr = sw + c*16;
        float acc = sbv[c];
#pragma unroll
        for (int i = 0; i < 16; ++i) acc += wr[i]*yv[i];
        size_t off = (((size_t)(b*NC + c))*NH + h)*NW + w;
        z[off] = x[off] + acc;
    }
}

// ---------------------------------------------------------------------------
// Kernel 5/6/7: BatchNorm training-mode stats + normalize
// ---------------------------------------------------------------------------
extern "C" __global__ void k_zero(float* __restrict__ stats)
{
    if (threadIdx.x < 2*NC) stats[threadIdx.x] = 0.f;
}

extern "C" __global__ __launch_bounds__(256)
void k_stats(const float* __restrict__ z, float* __restrict__ stats)
{
    int c = blockIdx.x, b = blockIdx.y;
    const float4* zp = (const float4*)(z + ((size_t)(b*NC + c))*NH*NW);
    float s = 0.f, s2 = 0.f;
    for (int i = threadIdx.x; i < NH*NW/4; i += 256) {
        float4 v = zp[i];
        s  += v.x + v.y + v.z + v.w;
        s2 += v.x*v.x + v.y*v.y + v.z*v.z + v.w*v.w;
    }
#pragma unroll
    for (int off = 32; off > 0; off >>= 1) {
        s  += __shfl_down(s, off);
        s2 += __shfl_down(s2, off);
    }
    __shared__ float red[8];
    int lane = threadIdx.x & 63, wv = threadIdx.x >> 6;
    if (lane == 0) { red[wv] = s; red[4+wv] = s2; }
    __syncthreads();
    if (threadIdx.x == 0) {
        atomicAdd(&stats[c],      red[0]+red[1]+red[2]+red[3]);
        atomicAdd(&stats[NC+c],   red[4]+red[5]+red[6]+red[7]);
    }
}

extern "C" __global__ __launch_bounds__(256)
void k_norm(const float* __restrict__ z, const float* __restrict__ stats,
            const float* __restrict__ gamma, const float* __restrict__ beta,
            float* __restrict__ out)
{
    size_t i4 = (size_t)blockIdx.x*256 + threadIdx.x;
    int c = (int)((i4 >> 12) & 63);
    const float inv_cnt = 1.f/65536.f;  // B*H*W
    float mean = stats[c]*inv_cnt;
    float var  = stats[NC+c]*inv_cnt - mean*mean;
    float rs = rsqrtf(var + 1e-5f);
    float ga = gamma[c]*rs;
    float be = beta[c] - mean*ga;
    float4 v = ((const float4*)z)[i4];
    ((float4*)out)[i4] = make_float4(v.x*ga+be, v.y*ga+be, v.z*ga+be, v.w*ga+be);
}

// ---------------------------------------------------------------------------
// Launch
// ---------------------------------------------------------------------------
extern "C" void kernel_launch(void* const* d_in, const int* in_sizes, int n_in,
                              void* d_out, int out_size, void* d_ws, size_t ws_size,
                              hipStream_t stream)
{
    const float* x     = (const float*)d_in[0];
    const float* gw    = (const float*)d_in[1];
    const float* gb    = (const float*)d_in[2];
    const float* tw    = (const float*)d_in[3];
    const float* tb    = (const float*)d_in[4];
    const float* pw    = (const float*)d_in[5];
    const float* pb    = (const float*)d_in[6];
    const float* ow    = (const float*)d_in[7];
    const float* ob    = (const float*)d_in[8];
    const float* gamma = (const float*)d_in[9];
    const float* beta  = (const float*)d_in[10];
    float* out = (float*)d_out;

    float* ws    = (float*)d_ws;
    float* th    = ws;                 // [4][4096][16]
    float* ph    = ws + (size_t)SEG;   // [4][4096][16] (phi transposed)
    float* g     = ws + (size_t)2*SEG; // [4][4096][16]
    float* yt    = ws + (size_t)3*SEG; // [4][16][4096]
    float* lp    = ws + (size_t)4*SEG; // [16][4][4096]
    float* stats = ws + (size_t)5*SEG; // [128]
    float* big   = stats + 128;        // accp [16][4][4096][16]  OR z [4][64][128][128]
    float* accp  = big;
    float* z     = big;                // disjoint lifetimes

    k_zero   <<<1, 128, 0, stream>>>(stats);
    k_proj   <<<64, 256, 0, stream>>>(x, gw, gb, tw, tb, pw, pb, th, ph, g);
    k_attn   <<<dim3(8, MS, NB), 256, 0, stream>>>(th, ph, g, accp, lp);
    k_combine<<<64, 256, 0, stream>>>(accp, lp, yt);
    k_out    <<<dim3(NH, NB), 128, 0, stream>>>(yt, x, ow, ob, z);
    k_stats  <<<dim3(NC, NB), 256, 0, stream>>>(z, stats);
    k_norm   <<<4096, 256, 0, stream>>>(z, stats, gamma, beta, out);
}

// Round 2
// 151.224 us; speedup vs baseline: 1.4614x; 1.4614x over previous
//
#include <hip/hip_runtime.h>
#include <math.h>

// Problem constants
#define NB 4      // batch
#define NC 64     // channels
#define NI 16     // inter-channels
#define NH 128    // height
#define NW 128    // width
#define ND 64     // downsampled h/w
#define NN 4096   // ND*ND pixels
#define KSPL 4    // key splits in attention

#define LOG2E 1.4426950408889634f

using bfrag = __attribute__((ext_vector_type(8))) short;   // 8 bf16 (4 VGPRs)
using ffrag = __attribute__((ext_vector_type(4))) float;   // 4 fp32 acc

#if __has_builtin(__builtin_amdgcn_exp2f)
#define EXP2(x) __builtin_amdgcn_exp2f(x)
#else
#define EXP2(x) exp2f(x)
#endif

__device__ __forceinline__ unsigned bf16rne(float f) {
    unsigned u = __float_as_uint(f);
    return (u + 0x7FFFu + ((u >> 16) & 1u)) >> 16;
}
__device__ __forceinline__ unsigned pk_rne(float lo, float hi) {
    return bf16rne(lo) | (bf16rne(hi) << 16);
}
// truncating pack (fast path for P values; bias analyzed ~negligible)
__device__ __forceinline__ unsigned pk_trunc(float lo, float hi) {
    return (__float_as_uint(lo) >> 16) | (__float_as_uint(hi) & 0xFFFF0000u);
}

// ---------------------------------------------------------------------------
// Kernel 1: fused downsample (point-sample at odd pixels) + theta/phi/g
// projections, emitted as PRE-SWIZZLED bf16 MFMA fragments.
//   th_sw[b][qtile16][lane][8bf16]: B-frag of S^T mfma: lane(quad,n): j ->
//       theta[query=n][ic=quad*8+j] * LOG2E  (quads 2,3 = zero pad)
//   phi_sw[b][kgroup16][lane][8bf16]: A-frag: lane(quad,r): j ->
//       phi[key(permuted)][ic=quad*8+j]   (quads 2,3 = zero pad)
//       key permutation within 32-chunk: group g row r -> natural 8*(r>>2)+4g+(r&3)
//   g_sw[b][chunk32][lane][8bf16]: B-frag of PV mfma: lane(quad,n): j ->
//       g[chunkkey=8*quad+j][ic=n]
// Also zeroes the BN stats buffer (block 0).
// ---------------------------------------------------------------------------
extern "C" __global__ __launch_bounds__(256)
void k_proj(const float* __restrict__ x,
            const float* __restrict__ gw, const float* __restrict__ gb,
            const float* __restrict__ tw, const float* __restrict__ tb,
            const float* __restrict__ pw, const float* __restrict__ pb,
            uint4* __restrict__ th_sw, uint4* __restrict__ phi_sw,
            uint4* __restrict__ g_sw, float* __restrict__ stats)
{
    __shared__ float swt[NC][48];  // [c][0:16)=theta [16:32)=phi [32:48)=g
    __shared__ float sb[48];
    __shared__ __align__(16) unsigned short gtile[16][256];  // [ic][pixel] bf16
    int tid = threadIdx.x;
    if (blockIdx.x == 0 && tid < 128) stats[tid] = 0.f;
    for (int idx = tid; idx < NI*NC; idx += 256) {
        int o = idx >> 6, c = idx & 63;
        swt[c][o]      = tw[idx];
        swt[c][16 + o] = pw[idx];
        swt[c][32 + o] = gw[idx];
    }
    if (tid < 16) { sb[tid] = tb[tid]; sb[16+tid] = pb[tid]; sb[32+tid] = gb[tid]; }
    __syncthreads();

    int bq = blockIdx.x * 256 + tid;   // 0..16383
    int b = bq >> 12, q = bq & 4095;
    int i = q >> 6, j = q & 63;
    const float* xp = x + (((size_t)(b*NC)*NH + (2*i+1))*NW + (2*j+1));
    float aT[16], aP[16], aG[16];
#pragma unroll
    for (int o = 0; o < 16; ++o) { aT[o] = 0.f; aP[o] = 0.f; aG[o] = 0.f; }
    for (int c = 0; c < NC; ++c) {
        float xd = xp[(size_t)c*NH*NW];
        const float* wr = swt[c];
#pragma unroll
        for (int o = 0; o < 16; ++o) aT[o] += xd*wr[o];
#pragma unroll
        for (int o = 0; o < 16; ++o) aP[o] += xd*wr[16+o];
#pragma unroll
        for (int o = 0; o < 16; ++o) aG[o] += xd*wr[32+o];
    }
#pragma unroll
    for (int o = 0; o < 16; ++o) {
        aT[o] = (aT[o] + sb[o]) * LOG2E;
        aP[o] =  aP[o] + sb[16+o];
        aG[o] =  aG[o] + sb[32+o];
    }

    const uint4 z4 = make_uint4(0u, 0u, 0u, 0u);
    // ---- theta: B-frag layout, query n = q&15, qtile = bq>>4 (global)
    {
        int n = q & 15;
        size_t base = (size_t)(bq >> 4) * 64;
        uint4 v0 = make_uint4(pk_rne(aT[0],aT[1]),  pk_rne(aT[2],aT[3]),
                              pk_rne(aT[4],aT[5]),  pk_rne(aT[6],aT[7]));
        uint4 v1 = make_uint4(pk_rne(aT[8],aT[9]),  pk_rne(aT[10],aT[11]),
                              pk_rne(aT[12],aT[13]),pk_rne(aT[14],aT[15]));
        th_sw[base +      n] = v0;
        th_sw[base + 16 + n] = v1;
        th_sw[base + 32 + n] = z4;
        th_sw[base + 48 + n] = z4;
    }
    // ---- phi: A-frag layout with key permutation
    {
        int w = q & 31;
        int gsel = (w >> 2) & 1;               // octet half -> group
        int r = ((w >> 3) << 2) | (w & 3);     // row within group
        size_t kgroup = (size_t)b*256 + ((q >> 5) << 1) + gsel;
        size_t base = kgroup * 64;
        uint4 v0 = make_uint4(pk_rne(aP[0],aP[1]),  pk_rne(aP[2],aP[3]),
                              pk_rne(aP[4],aP[5]),  pk_rne(aP[6],aP[7]));
        uint4 v1 = make_uint4(pk_rne(aP[8],aP[9]),  pk_rne(aP[10],aP[11]),
                              pk_rne(aP[12],aP[13]),pk_rne(aP[14],aP[15]));
        phi_sw[base +      r] = v0;
        phi_sw[base + 16 + r] = v1;
        phi_sw[base + 32 + r] = z4;
        phi_sw[base + 48 + r] = z4;
    }
    // ---- g: LDS transpose to B-frag layout
#pragma unroll
    for (int o = 0; o < 16; ++o) gtile[o][tid] = (unsigned short)bf16rne(aG[o]);
    __syncthreads();
    size_t gchunk0 = (size_t)b*128 + (size_t)(blockIdx.x & 15) * 8;
    for (int e = tid; e < 512; e += 256) {
        int c = e >> 6, L = e & 63, q8 = (L >> 4), n = L & 15;
        const uint4* src = (const uint4*)&gtile[n][c*32 + q8*8];
        g_sw[(gchunk0 + c)*64 + L] = *src;
    }
}

// ---------------------------------------------------------------------------
// Kernel 2: MFMA flash attention (max-free softmax; scores ~N(0,1)).
// Block: 256 thr = 4 waves; each wave: 16 queries x 1024 keys (ksplit).
// Per 32-key step: S^T = mfma(phiA/B, theta) -> exp2 -> pack -> P A-frag
// (layout lines up by construction) -> Y += mfma(P, V).
// Partials: accp[ks][b][q][16] (raw), lp[ks][b][q] (raw l).
// ---------------------------------------------------------------------------
extern "C" __global__ __launch_bounds__(256)
void k_attn(const uint4* __restrict__ th_sw, const uint4* __restrict__ phi_sw,
            const uint4* __restrict__ g_sw, float* __restrict__ accp,
            float* __restrict__ lp)
{
    __shared__ uint4 sphi[16*64];  // one 256-key chunk of phi frags (16 KB)
    __shared__ uint4 sg[8*64];     // one 256-key chunk of V frags (8 KB)
    __shared__ float sl[4][16];

    int tid = threadIdx.x;
    int wave = tid >> 6, lane = tid & 63;
    int quad = lane >> 4, low = lane & 15;
    int qgroup = blockIdx.x, ks = blockIdx.y, b = blockIdx.z;

    // per-wave fixed theta B-frag
    const bfrag* thF = (const bfrag*)th_sw;
    bfrag theta = thF[((size_t)b*256 + qgroup*4 + wave)*64 + lane];

    ffrag yacc = {0.f, 0.f, 0.f, 0.f};
    const ffrag zf = {0.f, 0.f, 0.f, 0.f};
    float lacc = 0.f;

    for (int chunk = 0; chunk < 4; ++chunk) {
        __syncthreads();
        const uint4* srcP = phi_sw + ((size_t)b*256 + ks*64 + chunk*16)*64;
        const uint4* srcG = g_sw   + ((size_t)b*128 + ks*32 + chunk*8 )*64;
#pragma unroll
        for (int it = 0; it < 4; ++it) sphi[it*256 + tid] = srcP[it*256 + tid];
#pragma unroll
        for (int it = 0; it < 2; ++it) sg[it*256 + tid]   = srcG[it*256 + tid];
        __syncthreads();

        const bfrag* sphiF = (const bfrag*)sphi;
        const bfrag* sgF   = (const bfrag*)sg;
#pragma unroll
        for (int s = 0; s < 8; ++s) {
            bfrag pA = sphiF[(s*2+0)*64 + lane];
            bfrag pB = sphiF[(s*2+1)*64 + lane];
            bfrag vf = sgF[s*64 + lane];
            ffrag sA = __builtin_amdgcn_mfma_f32_16x16x32_bf16(pA, theta, zf, 0, 0, 0);
            ffrag sB = __builtin_amdgcn_mfma_f32_16x16x32_bf16(pB, theta, zf, 0, 0, 0);
            float eA0 = EXP2(sA[0]), eA1 = EXP2(sA[1]), eA2 = EXP2(sA[2]), eA3 = EXP2(sA[3]);
            float eB0 = EXP2(sB[0]), eB1 = EXP2(sB[1]), eB2 = EXP2(sB[2]), eB3 = EXP2(sB[3]);
            lacc += ((eA0+eA1) + (eA2+eA3)) + ((eB0+eB1) + (eB2+eB3));
            union { unsigned u[4]; bfrag f; } pu;
            pu.u[0] = pk_trunc(eA0, eA1);
            pu.u[1] = pk_trunc(eA2, eA3);
            pu.u[2] = pk_trunc(eB0, eB1);
            pu.u[3] = pk_trunc(eB2, eB3);
            yacc = __builtin_amdgcn_mfma_f32_16x16x32_bf16(pu.f, vf, yacc, 0, 0, 0);
        }
    }

    // l: reduce across the 4 quads (lanes 16 apart hold same query col)
    lacc += __shfl_xor(lacc, 16, 64);
    lacc += __shfl_xor(lacc, 32, 64);
    if (lane < 16) sl[wave][lane] = lacc;
    __syncthreads();

    int qbase = qgroup*64 + wave*16;
    size_t pbase = ((size_t)ks*NB + b)*NN;
#pragma unroll
    for (int reg = 0; reg < 4; ++reg) {
        int qq = qbase + quad*4 + reg;
        accp[(pbase + qq)*16 + low] = yacc[reg];
    }
    if (lane < 16) lp[pbase + qbase + lane] = lacc;
}

// ---------------------------------------------------------------------------
// Kernel 3: combine partials (sum raw acc and l across splits), divide,
// store y transposed: yt[b][i][n].
// ---------------------------------------------------------------------------
extern "C" __global__ __launch_bounds__(256)
void k_combine(const float* __restrict__ accp, const float* __restrict__ lp,
               float* __restrict__ yt)
{
    int bq = blockIdx.x*256 + threadIdx.x;
    int b = bq >> 12, q = bq & 4095;
    float acc[16];
#pragma unroll
    for (int k = 0; k < 16; ++k) acc[k] = 0.f;
    float l = 0.f;
    for (int s = 0; s < KSPL; ++s) {
        const float4* ap = (const float4*)accp + (((size_t)s*NB + b)*NN + q)*4;
        float4 v0 = ap[0], v1 = ap[1], v2 = ap[2], v3 = ap[3];
        acc[0]+=v0.x;  acc[1]+=v0.y;  acc[2]+=v0.z;  acc[3]+=v0.w;
        acc[4]+=v1.x;  acc[5]+=v1.y;  acc[6]+=v1.z;  acc[7]+=v1.w;
        acc[8]+=v2.x;  acc[9]+=v2.y;  acc[10]+=v2.z; acc[11]+=v2.w;
        acc[12]+=v3.x; acc[13]+=v3.y; acc[14]+=v3.z; acc[15]+=v3.w;
        l += lp[((size_t)s*NB + b)*NN + q];
    }
    float inv = 1.f / l;
#pragma unroll
    for (int i = 0; i < 16; ++i)
        yt[((size_t)b*NI + i)*NN + q] = acc[i]*inv;
}

// ---------------------------------------------------------------------------
// Kernel 4: bilinear upsample + out-projection + residual: z = x + W.yup + b
// ---------------------------------------------------------------------------
extern "C" __global__ __launch_bounds__(128)
void k_out(const float* __restrict__ yt, const float* __restrict__ x,
           const float* __restrict__ ow, const float* __restrict__ ob,
           float* __restrict__ z)
{
    __shared__ float syup[NI][NW];  // 8 KB
    __shared__ float sw[NC*NI];     // 4 KB
    __shared__ float sbv[NC];
    int w = threadIdx.x, h = blockIdx.x, b = blockIdx.y;
    for (int idx = w; idx < NC*NI; idx += 128) sw[idx] = ow[idx];
    if (w < NC) sbv[w] = ob[w];

    float chf = h*0.5f - 0.5f;
    int h0 = (int)floorf(chf); float fh = chf - (float)h0;
    int h1 = h0 + 1; if (h1 > ND-1) h1 = ND-1; if (h0 < 0) h0 = 0;
    float cwf = w*0.5f - 0.5f;
    int w0 = (int)floorf(cwf); float fw = cwf - (float)w0;
    int w1 = w0 + 1; if (w1 > ND-1) w1 = ND-1; if (w0 < 0) w0 = 0;
    float w00=(1.f-fh)*(1.f-fw), w01=(1.f-fh)*fw, w10=fh*(1.f-fw), w11=fh*fw;
    for (int i = 0; i < NI; ++i) {
        const float* yp = yt + ((size_t)b*NI + i)*NN;
        syup[i][w] = w00*yp[h0*ND+w0] + w01*yp[h0*ND+w1]
                   + w10*yp[h1*ND+w0] + w11*yp[h1*ND+w1];
    }
    __syncthreads();

    float yv[16];
#pragma unroll
    for (int i = 0; i < 16; ++i) yv[i] = syup[i][w];
    for (int c = 0; c < NC; ++c) {
        const float* wr = sw + c*16;
        float acc = sbv[c];
#pragma unroll
        for (int i = 0; i < 16; ++i) acc += wr[i]*yv[i];
        size_t off = (((size_t)(b*NC + c))*NH + h)*NW + w;
        z[off] = x[off] + acc;
    }
}

// ---------------------------------------------------------------------------
// Kernel 5/6: BatchNorm training-mode stats + normalize
// ---------------------------------------------------------------------------
extern "C" __global__ __launch_bounds__(256)
void k_stats(const float* __restrict__ z, float* __restrict__ stats)
{
    int c = blockIdx.x, b = blockIdx.y;
    const float4* zp = (const float4*)(z + ((size_t)(b*NC + c))*NH*NW);
    float s = 0.f, s2 = 0.f;
    for (int i = threadIdx.x; i < NH*NW/4; i += 256) {
        float4 v = zp[i];
        s  += v.x + v.y + v.z + v.w;
        s2 += v.x*v.x + v.y*v.y + v.z*v.z + v.w*v.w;
    }
#pragma unroll
    for (int off = 32; off > 0; off >>= 1) {
        s  += __shfl_down(s, off);
        s2 += __shfl_down(s2, off);
    }
    __shared__ float red[8];
    int lane = threadIdx.x & 63, wv = threadIdx.x >> 6;
    if (lane == 0) { red[wv] = s; red[4+wv] = s2; }
    __syncthreads();
    if (threadIdx.x == 0) {
        atomicAdd(&stats[c],    red[0]+red[1]+red[2]+red[3]);
        atomicAdd(&stats[NC+c], red[4]+red[5]+red[6]+red[7]);
    }
}

extern "C" __global__ __launch_bounds__(256)
void k_norm(const float* __restrict__ z, const float* __restrict__ stats,
            const float* __restrict__ gamma, const float* __restrict__ beta,
            float* __restrict__ out)
{
    size_t i4 = (size_t)blockIdx.x*256 + threadIdx.x;
    int c = (int)((i4 >> 12) & 63);
    const float inv_cnt = 1.f/65536.f;  // B*H*W
    float mean = stats[c]*inv_cnt;
    float var  = stats[NC+c]*inv_cnt - mean*mean;
    float rs = rsqrtf(var + 1e-5f);
    float ga = gamma[c]*rs;
    float be = beta[c] - mean*ga;
    float4 v = ((const float4*)z)[i4];
    ((float4*)out)[i4] = make_float4(v.x*ga+be, v.y*ga+be, v.z*ga+be, v.w*ga+be);
}

// ---------------------------------------------------------------------------
// Launch
// ---------------------------------------------------------------------------
extern "C" void kernel_launch(void* const* d_in, const int* in_sizes, int n_in,
                              void* d_out, int out_size, void* d_ws, size_t ws_size,
                              hipStream_t stream)
{
    const float* x     = (const float*)d_in[0];
    const float* gw    = (const float*)d_in[1];
    const float* gb    = (const float*)d_in[2];
    const float* tw    = (const float*)d_in[3];
    const float* tb    = (const float*)d_in[4];
    const float* pw    = (const float*)d_in[5];
    const float* pb    = (const float*)d_in[6];
    const float* ow    = (const float*)d_in[7];
    const float* ob    = (const float*)d_in[8];
    const float* gamma = (const float*)d_in[9];
    const float* beta  = (const float*)d_in[10];
    float* out = (float*)d_out;

    // workspace layout (bytes)
    char* wsb = (char*)d_ws;
    uint4* th_sw  = (uint4*)(wsb);                    // 1 MB  (4*256*64*16B)
    uint4* phi_sw = (uint4*)(wsb + (1u<<20));         // 1 MB
    uint4* g_sw   = (uint4*)(wsb + (2u<<20));         // 512 KB (4*128*64*16B)
    float* yt     = (float*)(wsb + (2u<<20) + (512u<<10));        // 1 MB
    float* lp     = (float*)(wsb + (3u<<20) + (512u<<10));        // 256 KB
    float* stats  = (float*)(wsb + (3u<<20) + (768u<<10));        // 1 KB
    char*  big    =          wsb + (3u<<20) + (769u<<10);
    float* accp   = (float*)big;   // 4 MB  [4][4][4096][16]
    float* z      = (float*)big;   // 16.8 MB, aliased: used after accp is dead

    k_proj   <<<64, 256, 0, stream>>>(x, gw, gb, tw, tb, pw, pb,
                                      th_sw, phi_sw, g_sw, stats);
    k_attn   <<<dim3(64, KSPL, NB), 256, 0, stream>>>(th_sw, phi_sw, g_sw, accp, lp);
    k_combine<<<64, 256, 0, stream>>>(accp, lp, yt);
    k_out    <<<dim3(NH, NB), 128, 0, stream>>>(yt, x, ow, ob, z);
    k_stats  <<<dim3(NC, NB), 256, 0, stream>>>(z, stats);
    k_norm   <<<4096, 256, 0, stream>>>(z, stats, gamma, beta, out);
}

// Round 3
// 130.290 us; speedup vs baseline: 1.6962x; 1.1607x over previous
//
#include <hip/hip_runtime.h>
#include <math.h>

// Problem constants
#define NB 4      // batch
#define NC 64     // channels
#define NI 16     // inter-channels
#define NH 128    // height
#define NW 128    // width
#define ND 64     // downsampled h/w
#define NN 4096   // ND*ND pixels
#define KSPL 4    // key splits in attention

#define LOG2E 1.4426950408889634f

using bfrag  = __attribute__((ext_vector_type(8))) short;  // 8 bf16 (4 VGPRs)
using bfrag4 = __attribute__((ext_vector_type(4))) short;  // 4 bf16 (2 VGPRs)
using ffrag  = __attribute__((ext_vector_type(4))) float;  // 4 fp32 acc

#if __has_builtin(__builtin_amdgcn_exp2f)
#define EXP2(x) __builtin_amdgcn_exp2f(x)
#else
#define EXP2(x) exp2f(x)
#endif

__device__ __forceinline__ unsigned bf16rne(float f) {
    unsigned u = __float_as_uint(f);
    return (u + 0x7FFFu + ((u >> 16) & 1u)) >> 16;
}
__device__ __forceinline__ unsigned pk_rne(float lo, float hi) {
    return bf16rne(lo) | (bf16rne(hi) << 16);
}
__device__ __forceinline__ unsigned pk_trunc(float lo, float hi) {
    return (__float_as_uint(lo) >> 16) | (__float_as_uint(hi) & 0xFFFF0000u);
}

// QK^T MFMA: 16x16x16 bf16 (K = ic = 16, no zero-pad) with fallback.
__device__ __forceinline__ ffrag mfma_qk(bfrag4 a, bfrag4 b, ffrag c) {
#if __has_builtin(__builtin_amdgcn_mfma_f32_16x16x16bf16_1k)
    return __builtin_amdgcn_mfma_f32_16x16x16bf16_1k(a, b, c, 0, 0, 0);
#else
    union { bfrag4 h[2]; bfrag v; } ua, ub;
    bfrag4 zz = {0, 0, 0, 0};
    ua.h[0] = a; ua.h[1] = zz;
    ub.h[0] = b; ub.h[1] = zz;
    return __builtin_amdgcn_mfma_f32_16x16x32_bf16(ua.v, ub.v, c, 0, 0, 0);
#endif
}

// ---------------------------------------------------------------------------
// Kernel 1: fused downsample (point-sample at odd pixels) + theta/phi/g
// projections -> pre-swizzled bf16 MFMA fragments.
//   th_sw[b*256+qtile][lane]  uint2: theta[query=lane&15][ic=4*quad+j]*LOG2E
//   phi_sw[b*256+kgrp][lane]  uint2: phi[key(perm)][ic=4*quad+j]
//       key perm within 32-chunk: frag f, quad q, reg r <-> key 8q+4f+r
//   g_sw[b*128+chunk][lane]   uint4: g[key=8*quad+j][ic=lane&15]
// 256 blocks: block=(b, ds-row i); 4 threads/pixel split the 64-channel
// reduction, LDS-reduced (stride 49 = conflict-free). Block 0 zeroes stats.
// ---------------------------------------------------------------------------
extern "C" __global__ __launch_bounds__(256)
void k_proj(const float* __restrict__ x,
            const float* __restrict__ gw, const float* __restrict__ gb,
            const float* __restrict__ tw, const float* __restrict__ tb,
            const float* __restrict__ pw, const float* __restrict__ pb,
            uint2* __restrict__ th_sw, uint2* __restrict__ phi_sw,
            uint4* __restrict__ g_sw, float* __restrict__ stats)
{
    __shared__ float swt[NC][48];   // [c][0:16)=theta [16:32)=phi [32:48)=g
    __shared__ float sb[48];
    __shared__ float red[3][64][49];
    __shared__ __align__(16) unsigned short gtile[16][64];
    int tid = threadIdx.x;
    int b = blockIdx.x >> 6, i = blockIdx.x & 63;
    if (blockIdx.x == 0 && tid < 128) stats[tid] = 0.f;
    for (int idx = tid; idx < NI*NC; idx += 256) {
        int o = idx >> 6, c = idx & 63;
        swt[c][o]      = tw[idx];
        swt[c][16 + o] = pw[idx];
        swt[c][32 + o] = gw[idx];
    }
    if (tid < 16) { sb[tid] = tb[tid]; sb[16+tid] = pb[tid]; sb[32+tid] = gb[tid]; }
    __syncthreads();

    int j = tid & 63, part = tid >> 6;
    const float* xp = x + (((size_t)(b*NC + part*16))*NH + (2*i+1))*NW + (2*j+1);
    float a[48];
#pragma unroll
    for (int k = 0; k < 48; ++k) a[k] = 0.f;
    for (int cc = 0; cc < 16; ++cc) {
        float xd = xp[(size_t)cc*NH*NW];
        const float* wr = swt[part*16 + cc];
#pragma unroll
        for (int k = 0; k < 48; ++k) a[k] += xd*wr[k];
    }
    if (part != 0) {
#pragma unroll
        for (int k = 0; k < 48; ++k) red[part-1][j][k] = a[k];
    }
    __syncthreads();
    if (part == 0) {
        float aT[16], aP[16], aG[16];
#pragma unroll
        for (int o = 0; o < 16; ++o) {
            float vT = a[o]    + red[0][j][o]    + red[1][j][o]    + red[2][j][o];
            float vP = a[16+o] + red[0][j][16+o] + red[1][j][16+o] + red[2][j][16+o];
            float vG = a[32+o] + red[0][j][32+o] + red[1][j][32+o] + red[2][j][32+o];
            aT[o] = (vT + sb[o]) * LOG2E;
            aP[o] =  vP + sb[16+o];
            aG[o] =  vG + sb[32+o];
        }
        int q = i*64 + j;
        // theta B-frag
        int n = j & 15;
        size_t qtile = (size_t)b*256 + (q >> 4);
#pragma unroll
        for (int qd = 0; qd < 4; ++qd)
            th_sw[qtile*64 + qd*16 + n] =
                make_uint2(pk_rne(aT[4*qd], aT[4*qd+1]), pk_rne(aT[4*qd+2], aT[4*qd+3]));
        // phi A-frag with key permutation
        int wk = j & 31;
        int f = (wk >> 2) & 1;
        int r = ((wk >> 3) << 2) | (wk & 3);
        size_t kgrp = (size_t)b*256 + (q >> 5)*2 + f;
#pragma unroll
        for (int qd = 0; qd < 4; ++qd)
            phi_sw[kgrp*64 + qd*16 + r] =
                make_uint2(pk_rne(aP[4*qd], aP[4*qd+1]), pk_rne(aP[4*qd+2], aP[4*qd+3]));
        // g -> LDS tile for transpose
#pragma unroll
        for (int o = 0; o < 16; ++o) gtile[o][j] = (unsigned short)bf16rne(aG[o]);
    }
    __syncthreads();
    if (tid < 128) {
        int c2 = tid >> 6, L = tid & 63;
        int n = L & 15, q8 = L >> 4;
        const uint4* src = (const uint4*)&gtile[n][c2*32 + q8*8];
        g_sw[((size_t)b*128 + i*2 + c2)*64 + L] = *src;
    }
}

// ---------------------------------------------------------------------------
// Kernel 2: MFMA flash attention (max-free softmax; scores ~N(0,1)).
// 4 waves/block, 16 queries/wave, KSPL key-splits of 1024 keys.
// Per 32-key step: two 16x16x16 QK mfmas -> exp2 -> pack (layout lines up
// with PV A-frag by construction) -> one 16x16x32 PV mfma.
// ---------------------------------------------------------------------------
extern "C" __global__ __launch_bounds__(256, 4)
void k_attn(const uint2* __restrict__ th_sw, const uint2* __restrict__ phi_sw,
            const uint4* __restrict__ g_sw, float* __restrict__ accp,
            float* __restrict__ lp)
{
    __shared__ __align__(16) uint2 sphi[16*64];  // 8 KB: 16 key-groups
    __shared__ __align__(16) uint4 sg[8*64];     // 8 KB: 8 V chunks
    int tid = threadIdx.x;
    int wave = tid >> 6, lane = tid & 63;
    int quad = lane >> 4, low = lane & 15;
    int qgroup = blockIdx.x, ks = blockIdx.y, b = blockIdx.z;

    union { uint2 u; bfrag4 f; } thu;
    thu.u = th_sw[((size_t)b*256 + qgroup*4 + wave)*64 + lane];
    bfrag4 theta = thu.f;

    ffrag yacc = {0.f, 0.f, 0.f, 0.f};
    const ffrag zf = {0.f, 0.f, 0.f, 0.f};
    float lacc = 0.f;

    for (int chunk = 0; chunk < 4; ++chunk) {
        __syncthreads();
        const uint4* srcP = (const uint4*)(phi_sw + ((size_t)b*256 + ks*64 + chunk*16)*64);
        const uint4* srcG = g_sw + ((size_t)b*128 + ks*32 + chunk*8)*64;
        ((uint4*)sphi)[tid]       = srcP[tid];
        ((uint4*)sphi)[256 + tid] = srcP[256 + tid];
        sg[tid]       = srcG[tid];
        sg[256 + tid] = srcG[256 + tid];
        __syncthreads();

        const bfrag4* sphiF = (const bfrag4*)sphi;
        const bfrag*  sgF   = (const bfrag*)sg;
#pragma unroll
        for (int s = 0; s < 8; ++s) {
            bfrag4 pA = sphiF[(2*s+0)*64 + lane];
            bfrag4 pB = sphiF[(2*s+1)*64 + lane];
            bfrag  vf = sgF[s*64 + lane];
            ffrag sA = mfma_qk(pA, theta, zf);
            ffrag sB = mfma_qk(pB, theta, zf);
            float eA0 = EXP2(sA[0]), eA1 = EXP2(sA[1]), eA2 = EXP2(sA[2]), eA3 = EXP2(sA[3]);
            float eB0 = EXP2(sB[0]), eB1 = EXP2(sB[1]), eB2 = EXP2(sB[2]), eB3 = EXP2(sB[3]);
            lacc += ((eA0+eA1) + (eA2+eA3)) + ((eB0+eB1) + (eB2+eB3));
            union { unsigned u[4]; bfrag f; } pu;
            pu.u[0] = pk_trunc(eA0, eA1);
            pu.u[1] = pk_trunc(eA2, eA3);
            pu.u[2] = pk_trunc(eB0, eB1);
            pu.u[3] = pk_trunc(eB2, eB3);
            yacc = __builtin_amdgcn_mfma_f32_16x16x32_bf16(pu.f, vf, yacc, 0, 0, 0);
        }
    }

    // l: reduce across quads (lanes 16 apart share a query column)
    lacc += __shfl_xor(lacc, 16, 64);
    lacc += __shfl_xor(lacc, 32, 64);

    int qbase = qgroup*64 + wave*16;
    size_t pbase = ((size_t)ks*NB + b)*NN;
#pragma unroll
    for (int reg = 0; reg < 4; ++reg)
        accp[(pbase + qbase + quad*4 + reg)*16 + low] = yacc[reg];
    if (lane < 16) lp[pbase + qbase + lane] = lacc;
}

// ---------------------------------------------------------------------------
// Kernel 3: fused combine (sum split partials, softmax divide) + bilinear
// upsample + out-projection + residual: z = x + W.yup + bias.
// Block = (b, output-row-pair hp): rows 2hp, 2hp+1 need ds rows {hp-1, hp}.
// ---------------------------------------------------------------------------
extern "C" __global__ __launch_bounds__(256)
void k_outz(const float* __restrict__ accp, const float* __restrict__ lp,
            const float* __restrict__ x, const float* __restrict__ ow,
            const float* __restrict__ ob, float* __restrict__ z)
{
    __shared__ float syd[2][NI][ND];  // 8 KB combined y at ds rows
    __shared__ float sl[2][ND];
    __shared__ float swv[NC*NI];      // 4 KB
    __shared__ float sbv[NC];
    int t = threadIdx.x;
    int hp = blockIdx.x, b = blockIdx.y;
    for (int idx = t; idx < NC*NI; idx += 256) swv[idx] = ow[idx];
    if (t < NC) sbv[t] = ob[t];

    // phase A: combine accp/lp -> syd (2 rows x 16 ic x 64 cols)
    {
        int r = t >> 7, col = (t >> 1) & 63, half = t & 1;
        int row = (r == 0) ? (hp > 0 ? hp-1 : 0) : hp;
        int q = row*64 + col;
        float4 a0 = make_float4(0.f,0.f,0.f,0.f), a1 = a0;
        float lsum = 0.f;
        for (int ks = 0; ks < KSPL; ++ks) {
            const float4* ap = (const float4*)accp + (((size_t)ks*NB + b)*NN + q)*4 + 2*half;
            float4 v0 = ap[0], v1 = ap[1];
            a0.x += v0.x; a0.y += v0.y; a0.z += v0.z; a0.w += v0.w;
            a1.x += v1.x; a1.y += v1.y; a1.z += v1.z; a1.w += v1.w;
            if (half == 0) lsum += lp[((size_t)ks*NB + b)*NN + q];
        }
        if (half == 0) sl[r][col] = lsum;
        __syncthreads();
        float inv = 1.f / sl[r][col];
        int i0 = 8*half;
        syd[r][i0+0][col] = a0.x*inv; syd[r][i0+1][col] = a0.y*inv;
        syd[r][i0+2][col] = a0.z*inv; syd[r][i0+3][col] = a0.w*inv;
        syd[r][i0+4][col] = a1.x*inv; syd[r][i0+5][col] = a1.y*inv;
        syd[r][i0+6][col] = a1.z*inv; syd[r][i0+7][col] = a1.w*inv;
    }
    __syncthreads();

    // phase B: upsample + out-proj + residual
    int w = t & 127, hsel = t >> 7;
    int h = 2*hp + hsel;
    float wh0 = hsel ? 0.f : 0.5f;
    float wh1 = hsel ? 1.f : 0.5f;
    int c0, c1; float wc0, wc1;
    if (w & 1) { c0 = c1 = (w-1) >> 1; wc0 = 1.f; wc1 = 0.f; }
    else       { c1 = w >> 1; c0 = c1 ? c1-1 : 0; wc0 = 0.5f; wc1 = 0.5f; }
    float yv[16];
#pragma unroll
    for (int i = 0; i < 16; ++i)
        yv[i] = wh0*(wc0*syd[0][i][c0] + wc1*syd[0][i][c1])
              + wh1*(wc0*syd[1][i][c0] + wc1*syd[1][i][c1]);

    const float* xb = x + (((size_t)(b*NC))*NH + h)*NW + w;
    float* zb       = z + (((size_t)(b*NC))*NH + h)*NW + w;
    for (int c = 0; c < NC; ++c) {
        const float* wr = swv + c*16;
        float acc = sbv[c];
#pragma unroll
        for (int i = 0; i < 16; ++i) acc += wr[i]*yv[i];
        zb[(size_t)c*NH*NW] = xb[(size_t)c*NH*NW] + acc;
    }
}

// ---------------------------------------------------------------------------
// Kernel 4/5: BatchNorm training-mode stats + normalize
// ---------------------------------------------------------------------------
extern "C" __global__ __launch_bounds__(256)
void k_stats(const float* __restrict__ z, float* __restrict__ stats)
{
    int c = blockIdx.x, b = blockIdx.y;
    const float4* zp = (const float4*)(z + ((size_t)(b*NC + c))*NH*NW);
    float s = 0.f, s2 = 0.f;
    for (int i = threadIdx.x; i < NH*NW/4; i += 256) {
        float4 v = zp[i];
        s  += v.x + v.y + v.z + v.w;
        s2 += v.x*v.x + v.y*v.y + v.z*v.z + v.w*v.w;
    }
#pragma unroll
    for (int off = 32; off > 0; off >>= 1) {
        s  += __shfl_down(s, off);
        s2 += __shfl_down(s2, off);
    }
    __shared__ float red[8];
    int lane = threadIdx.x & 63, wv = threadIdx.x >> 6;
    if (lane == 0) { red[wv] = s; red[4+wv] = s2; }
    __syncthreads();
    if (threadIdx.x == 0) {
        atomicAdd(&stats[c],    red[0]+red[1]+red[2]+red[3]);
        atomicAdd(&stats[NC+c], red[4]+red[5]+red[6]+red[7]);
    }
}

extern "C" __global__ __launch_bounds__(256)
void k_norm(const float* __restrict__ z, const float* __restrict__ stats,
            const float* __restrict__ gamma, const float* __restrict__ beta,
            float* __restrict__ out)
{
    size_t i4 = (size_t)blockIdx.x*256 + threadIdx.x;
    int c = (int)((i4 >> 12) & 63);
    const float inv_cnt = 1.f/65536.f;  // B*H*W
    float mean = stats[c]*inv_cnt;
    float var  = stats[NC+c]*inv_cnt - mean*mean;
    float rs = rsqrtf(var + 1e-5f);
    float ga = gamma[c]*rs;
    float be = beta[c] - mean*ga;
    float4 v = ((const float4*)z)[i4];
    ((float4*)out)[i4] = make_float4(v.x*ga+be, v.y*ga+be, v.z*ga+be, v.w*ga+be);
}

// ---------------------------------------------------------------------------
// Launch
// ---------------------------------------------------------------------------
extern "C" void kernel_launch(void* const* d_in, const int* in_sizes, int n_in,
                              void* d_out, int out_size, void* d_ws, size_t ws_size,
                              hipStream_t stream)
{
    const float* x     = (const float*)d_in[0];
    const float* gw    = (const float*)d_in[1];
    const float* gb    = (const float*)d_in[2];
    const float* tw    = (const float*)d_in[3];
    const float* tb    = (const float*)d_in[4];
    const float* pw    = (const float*)d_in[5];
    const float* pb    = (const float*)d_in[6];
    const float* ow    = (const float*)d_in[7];
    const float* ob    = (const float*)d_in[8];
    const float* gamma = (const float*)d_in[9];
    const float* beta  = (const float*)d_in[10];
    float* out = (float*)d_out;

    // workspace layout (bytes)
    char* wsb = (char*)d_ws;
    uint2* th_sw  = (uint2*)(wsb);                       // 512 KB
    uint2* phi_sw = (uint2*)(wsb + (512u<<10));          // 512 KB
    uint4* g_sw   = (uint4*)(wsb + (1024u<<10));         // 512 KB
    float* lp     = (float*)(wsb + (1536u<<10));         // 256 KB
    float* stats  = (float*)(wsb + (1792u<<10));         // 1 KB
    float* accp   = (float*)(wsb + (2048u<<10));         // 4 MB [4][4][4096][16]
    float* z      = (float*)(wsb + (6u<<20) + (256u<<10)); // 16.8 MB (no alias)

    k_proj <<<256, 256, 0, stream>>>(x, gw, gb, tw, tb, pw, pb,
                                     th_sw, phi_sw, g_sw, stats);
    k_attn <<<dim3(64, KSPL, NB), 256, 0, stream>>>(th_sw, phi_sw, g_sw, accp, lp);
    k_outz <<<dim3(64, NB), 256, 0, stream>>>(accp, lp, x, ow, ob, z);
    k_stats<<<dim3(NC, NB), 256, 0, stream>>>(z, stats);
    k_norm <<<4096, 256, 0, stream>>>(z, stats, gamma, beta, out);
}

// Round 5
// 126.959 us; speedup vs baseline: 1.7407x; 1.0262x over previous
//
#include <hip/hip_runtime.h>
#include <math.h>

// Problem constants
#define NB 4      // batch
#define NC 64     // channels
#define NI 16     // inter-channels
#define NH 128    // height
#define NW 128    // width
#define ND 64     // downsampled h/w
#define NN 4096   // ND*ND pixels
#define KSPL 4    // key splits in attention

#define LOG2E 1.4426950408889634f

using bfrag  = __attribute__((ext_vector_type(8))) short;  // 8 bf16 (4 VGPRs)
using bfrag4 = __attribute__((ext_vector_type(4))) short;  // 4 bf16 (2 VGPRs)
using ffrag  = __attribute__((ext_vector_type(4))) float;  // 4 fp32 acc

#if __has_builtin(__builtin_amdgcn_exp2f)
#define EXP2(x) __builtin_amdgcn_exp2f(x)
#else
#define EXP2(x) exp2f(x)
#endif

__device__ __forceinline__ unsigned bf16rne(float f) {
    unsigned u = __float_as_uint(f);
    return (u + 0x7FFFu + ((u >> 16) & 1u)) >> 16;
}
__device__ __forceinline__ unsigned pk_rne(float lo, float hi) {
    return bf16rne(lo) | (bf16rne(hi) << 16);
}
__device__ __forceinline__ unsigned pk_trunc(float lo, float hi) {
    return (__float_as_uint(lo) >> 16) | (__float_as_uint(hi) & 0xFFFF0000u);
}

// QK^T MFMA: 16x16x16 bf16 (K = ic = 16, no zero-pad) with fallback.
__device__ __forceinline__ ffrag mfma_qk(bfrag4 a, bfrag4 b, ffrag c) {
#if __has_builtin(__builtin_amdgcn_mfma_f32_16x16x16bf16_1k)
    return __builtin_amdgcn_mfma_f32_16x16x16bf16_1k(a, b, c, 0, 0, 0);
#else
    union { bfrag4 h[2]; bfrag v; } ua, ub;
    bfrag4 zz = {0, 0, 0, 0};
    ua.h[0] = a; ua.h[1] = zz;
    ub.h[0] = b; ub.h[1] = zz;
    return __builtin_amdgcn_mfma_f32_16x16x32_bf16(ua.v, ub.v, c, 0, 0, 0);
#endif
}

// ---------------------------------------------------------------------------
// Kernel 1: fused downsample (point-sample at odd pixels) + theta/phi/g
// projections -> pre-swizzled bf16 MFMA fragments. Block 0 zeroes the 8-way
// shadow stats buffer (8*128 floats).
// ---------------------------------------------------------------------------
extern "C" __global__ __launch_bounds__(256)
void k_proj(const float* __restrict__ x,
            const float* __restrict__ gw, const float* __restrict__ gb,
            const float* __restrict__ tw, const float* __restrict__ tb,
            const float* __restrict__ pw, const float* __restrict__ pb,
            uint2* __restrict__ th_sw, uint2* __restrict__ phi_sw,
            uint4* __restrict__ g_sw, float* __restrict__ shstats)
{
    __shared__ float swt[NC][48];   // [c][0:16)=theta [16:32)=phi [32:48)=g
    __shared__ float sb[48];
    __shared__ float red[3][64][49];
    __shared__ __align__(16) unsigned short gtile[16][64];
    int tid = threadIdx.x;
    int b = blockIdx.x >> 6, i = blockIdx.x & 63;
    if (blockIdx.x == 0) {
#pragma unroll
        for (int k = 0; k < 4; ++k) shstats[tid + k*256] = 0.f;
    }
    for (int idx = tid; idx < NI*NC; idx += 256) {
        int o = idx >> 6, c = idx & 63;
        swt[c][o]      = tw[idx];
        swt[c][16 + o] = pw[idx];
        swt[c][32 + o] = gw[idx];
    }
    if (tid < 16) { sb[tid] = tb[tid]; sb[16+tid] = pb[tid]; sb[32+tid] = gb[tid]; }
    __syncthreads();

    int j = tid & 63, part = tid >> 6;
    const float* xp = x + (((size_t)(b*NC + part*16))*NH + (2*i+1))*NW + (2*j+1);
    float a[48];
#pragma unroll
    for (int k = 0; k < 48; ++k) a[k] = 0.f;
    for (int cc = 0; cc < 16; ++cc) {
        float xd = xp[(size_t)cc*NH*NW];
        const float* wr = swt[part*16 + cc];
#pragma unroll
        for (int k = 0; k < 48; ++k) a[k] += xd*wr[k];
    }
    if (part != 0) {
#pragma unroll
        for (int k = 0; k < 48; ++k) red[part-1][j][k] = a[k];
    }
    __syncthreads();
    if (part == 0) {
        float aT[16], aP[16], aG[16];
#pragma unroll
        for (int o = 0; o < 16; ++o) {
            float vT = a[o]    + red[0][j][o]    + red[1][j][o]    + red[2][j][o];
            float vP = a[16+o] + red[0][j][16+o] + red[1][j][16+o] + red[2][j][16+o];
            float vG = a[32+o] + red[0][j][32+o] + red[1][j][32+o] + red[2][j][32+o];
            aT[o] = (vT + sb[o]) * LOG2E;
            aP[o] =  vP + sb[16+o];
            aG[o] =  vG + sb[32+o];
        }
        int q = i*64 + j;
        // theta B-frag
        int n = j & 15;
        size_t qtile = (size_t)b*256 + (q >> 4);
#pragma unroll
        for (int qd = 0; qd < 4; ++qd)
            th_sw[qtile*64 + qd*16 + n] =
                make_uint2(pk_rne(aT[4*qd], aT[4*qd+1]), pk_rne(aT[4*qd+2], aT[4*qd+3]));
        // phi A-frag with key permutation
        int wk = j & 31;
        int f = (wk >> 2) & 1;
        int r = ((wk >> 3) << 2) | (wk & 3);
        size_t kgrp = (size_t)b*256 + (q >> 5)*2 + f;
#pragma unroll
        for (int qd = 0; qd < 4; ++qd)
            phi_sw[kgrp*64 + qd*16 + r] =
                make_uint2(pk_rne(aP[4*qd], aP[4*qd+1]), pk_rne(aP[4*qd+2], aP[4*qd+3]));
        // g -> LDS tile for transpose
#pragma unroll
        for (int o = 0; o < 16; ++o) gtile[o][j] = (unsigned short)bf16rne(aG[o]);
    }
    __syncthreads();
    if (tid < 128) {
        int c2 = tid >> 6, L = tid & 63;
        int n = L & 15, q8 = L >> 4;
        const uint4* src = (const uint4*)&gtile[n][c2*32 + q8*8];
        g_sw[((size_t)b*128 + i*2 + c2)*64 + L] = *src;
    }
}

// ---------------------------------------------------------------------------
// Kernel 2: MFMA flash attention (max-free softmax; scores ~N(0,1)).
// 4 waves/block, 16 queries/wave, KSPL key-splits of 1024 keys.
// ---------------------------------------------------------------------------
extern "C" __global__ __launch_bounds__(256, 4)
void k_attn(const uint2* __restrict__ th_sw, const uint2* __restrict__ phi_sw,
            const uint4* __restrict__ g_sw, float* __restrict__ accp,
            float* __restrict__ lp)
{
    __shared__ __align__(16) uint2 sphi[16*64];  // 8 KB: 16 key-groups
    __shared__ __align__(16) uint4 sg[8*64];     // 8 KB: 8 V chunks
    int tid = threadIdx.x;
    int wave = tid >> 6, lane = tid & 63;
    int quad = lane >> 4, low = lane & 15;
    int qgroup = blockIdx.x, ks = blockIdx.y, b = blockIdx.z;

    union { uint2 u; bfrag4 f; } thu;
    thu.u = th_sw[((size_t)b*256 + qgroup*4 + wave)*64 + lane];
    bfrag4 theta = thu.f;

    ffrag yacc = {0.f, 0.f, 0.f, 0.f};
    const ffrag zf = {0.f, 0.f, 0.f, 0.f};
    float lacc = 0.f;

    for (int chunk = 0; chunk < 4; ++chunk) {
        __syncthreads();
        const uint4* srcP = (const uint4*)(phi_sw + ((size_t)b*256 + ks*64 + chunk*16)*64);
        const uint4* srcG = g_sw + ((size_t)b*128 + ks*32 + chunk*8)*64;
        ((uint4*)sphi)[tid]       = srcP[tid];
        ((uint4*)sphi)[256 + tid] = srcP[256 + tid];
        sg[tid]       = srcG[tid];
        sg[256 + tid] = srcG[256 + tid];
        __syncthreads();

        const bfrag4* sphiF = (const bfrag4*)sphi;
        const bfrag*  sgF   = (const bfrag*)sg;
#pragma unroll
        for (int s = 0; s < 8; ++s) {
            bfrag4 pA = sphiF[(2*s+0)*64 + lane];
            bfrag4 pB = sphiF[(2*s+1)*64 + lane];
            bfrag  vf = sgF[s*64 + lane];
            ffrag sA = mfma_qk(pA, theta, zf);
            ffrag sB = mfma_qk(pB, theta, zf);
            float eA0 = EXP2(sA[0]), eA1 = EXP2(sA[1]), eA2 = EXP2(sA[2]), eA3 = EXP2(sA[3]);
            float eB0 = EXP2(sB[0]), eB1 = EXP2(sB[1]), eB2 = EXP2(sB[2]), eB3 = EXP2(sB[3]);
            lacc += ((eA0+eA1) + (eA2+eA3)) + ((eB0+eB1) + (eB2+eB3));
            union { unsigned u[4]; bfrag f; } pu;
            pu.u[0] = pk_trunc(eA0, eA1);
            pu.u[1] = pk_trunc(eA2, eA3);
            pu.u[2] = pk_trunc(eB0, eB1);
            pu.u[3] = pk_trunc(eB2, eB3);
            yacc = __builtin_amdgcn_mfma_f32_16x16x32_bf16(pu.f, vf, yacc, 0, 0, 0);
        }
    }

    // l: reduce across quads (lanes 16 apart share a query column)
    lacc += __shfl_xor(lacc, 16, 64);
    lacc += __shfl_xor(lacc, 32, 64);

    int qbase = qgroup*64 + wave*16;
    size_t pbase = ((size_t)ks*NB + b)*NN;
#pragma unroll
    for (int reg = 0; reg < 4; ++reg)
        accp[(pbase + qbase + quad*4 + reg)*16 + low] = yacc[reg];
    if (lane < 16) lp[pbase + qbase + lane] = lacc;
}

// ---------------------------------------------------------------------------
// Kernel 3: fused combine + upsample + out-proj + residual + BN-stats.
// z written to global once; per-channel partial sums via LDS slab transpose
// (stride 257, oct-rotated reads -> conflict-free), octet shuffle reduce,
// 2 atomics/channel into one of 8 shadow accumulators.
// Block = (hp, b): output rows 2hp, 2hp+1.
// ---------------------------------------------------------------------------
extern "C" __global__ __launch_bounds__(256)
void k_outz(const float* __restrict__ accp, const float* __restrict__ lp,
            const float* __restrict__ x, const float* __restrict__ ow,
            const float* __restrict__ ob, float* __restrict__ z,
            float* __restrict__ shstats)
{
    __shared__ float slab[32*257];    // 32.1 KB z-transpose slab
    __shared__ float syd[2][NI][ND];  // 8 KB combined y at ds rows
    __shared__ float sl[2][ND];
    __shared__ float swv[NC*NI];      // 4 KB
    __shared__ float sbv[NC];
    int t = threadIdx.x;
    int hp = blockIdx.x, b = blockIdx.y;
    for (int idx = t; idx < NC*NI; idx += 256) swv[idx] = ow[idx];
    if (t < NC) sbv[t] = ob[t];

    // phase A: combine accp/lp -> syd (2 ds rows x 16 ic x 64 cols)
    {
        int r = t >> 7, col = (t >> 1) & 63, half = t & 1;
        int row = (r == 0) ? (hp > 0 ? hp-1 : 0) : hp;
        int q = row*64 + col;
        float4 a0 = make_float4(0.f,0.f,0.f,0.f), a1 = a0;
        float lsum = 0.f;
        for (int ks = 0; ks < KSPL; ++ks) {
            const float4* ap = (const float4*)accp + (((size_t)ks*NB + b)*NN + q)*4 + 2*half;
            float4 v0 = ap[0], v1 = ap[1];
            a0.x += v0.x; a0.y += v0.y; a0.z += v0.z; a0.w += v0.w;
            a1.x += v1.x; a1.y += v1.y; a1.z += v1.z; a1.w += v1.w;
            if (half == 0) lsum += lp[((size_t)ks*NB + b)*NN + q];
        }
        if (half == 0) sl[r][col] = lsum;
        __syncthreads();
        float inv = 1.f / sl[r][col];
        int i0 = 8*half;
        syd[r][i0+0][col] = a0.x*inv; syd[r][i0+1][col] = a0.y*inv;
        syd[r][i0+2][col] = a0.z*inv; syd[r][i0+3][col] = a0.w*inv;
        syd[r][i0+4][col] = a1.x*inv; syd[r][i0+5][col] = a1.y*inv;
        syd[r][i0+6][col] = a1.z*inv; syd[r][i0+7][col] = a1.w*inv;
    }
    __syncthreads();

    // phase B: upsample + out-proj + residual -> z in registers, store once
    int w = t & 127, hsel = t >> 7;
    int h = 2*hp + hsel;
    float wh0 = hsel ? 0.f : 0.5f;
    float wh1 = hsel ? 1.f : 0.5f;
    int c0, c1; float wc0, wc1;
    if (w & 1) { c0 = c1 = (w-1) >> 1; wc0 = 1.f; wc1 = 0.f; }
    else       { c1 = w >> 1; c0 = c1 ? c1-1 : 0; wc0 = 0.5f; wc1 = 0.5f; }
    float yv[16];
#pragma unroll
    for (int i = 0; i < 16; ++i)
        yv[i] = wh0*(wc0*syd[0][i][c0] + wc1*syd[0][i][c1])
              + wh1*(wc0*syd[1][i][c0] + wc1*syd[1][i][c1]);

    const float* xb = x + (((size_t)(b*NC))*NH + h)*NW + w;
    float* zb       = z + (((size_t)(b*NC))*NH + h)*NW + w;
    float zreg[64];
#pragma unroll
    for (int c = 0; c < NC; ++c) {
        const float* wr = swv + c*16;
        float acc = sbv[c];
#pragma unroll
        for (int i = 0; i < 16; ++i) acc += wr[i]*yv[i];
        zreg[c] = xb[(size_t)c*NH*NW] + acc;
        zb[(size_t)c*NH*NW] = zreg[c];
    }

    // phase C: BN partial stats via slab transpose + shadow atomics
    float* shadow = shstats + ((((unsigned)b << 6) + (unsigned)hp) & 7u)*128;
    int c32 = t >> 3, oct = t & 7;
#pragma unroll
    for (int half = 0; half < 2; ++half) {
        __syncthreads();
#pragma unroll
        for (int cc = 0; cc < 32; ++cc)
            slab[cc*257 + t] = zreg[half*32 + cc];
        __syncthreads();
        float s = 0.f, s2 = 0.f;
#pragma unroll
        for (int k = 0; k < 32; ++k) {
            int p2 = oct*32 + ((k + 4*oct) & 31);
            float v = slab[c32*257 + p2];
            s += v; s2 += v*v;
        }
        s  += __shfl_xor(s, 1);  s  += __shfl_xor(s, 2);  s  += __shfl_xor(s, 4);
        s2 += __shfl_xor(s2, 1); s2 += __shfl_xor(s2, 2); s2 += __shfl_xor(s2, 4);
        if (oct == 0) atomicAdd(shadow + half*32 + c32, s);
        if (oct == 1) atomicAdd(shadow + 64 + half*32 + c32, s2);
    }
}

// ---------------------------------------------------------------------------
// Kernel 4: fold 8 shadow stat accumulators, normalize z -> out.
// 1024 blocks x 256 thr, 4 float4 per thread.
// ---------------------------------------------------------------------------
extern "C" __global__ __launch_bounds__(256)
void k_norm(const float* __restrict__ z, const float* __restrict__ shstats,
            const float* __restrict__ gamma, const float* __restrict__ beta,
            float* __restrict__ out)
{
    __shared__ float sga[NC], sbe[NC];
    int t = threadIdx.x;
    if (t < NC) {
        float s = 0.f, s2 = 0.f;
#pragma unroll
        for (int sh = 0; sh < 8; ++sh) {
            s  += shstats[sh*128 + t];
            s2 += shstats[sh*128 + 64 + t];
        }
        const float inv_cnt = 1.f/65536.f;  // B*H*W
        float mean = s*inv_cnt;
        float var  = s2*inv_cnt - mean*mean;
        float rs = rsqrtf(var + 1e-5f);
        float ga = gamma[t]*rs;
        sga[t] = ga;
        sbe[t] = beta[t] - mean*ga;
    }
    __syncthreads();
#pragma unroll
    for (int it = 0; it < 4; ++it) {
        size_t i4 = ((size_t)blockIdx.x*4 + it)*256 + t;
        int c = (int)((i4 >> 12) & 63);
        float4 v = ((const float4*)z)[i4];
        float ga = sga[c], be = sbe[c];
        ((float4*)out)[i4] = make_float4(v.x*ga+be, v.y*ga+be, v.z*ga+be, v.w*ga+be);
    }
}

// ---------------------------------------------------------------------------
// Launch
// ---------------------------------------------------------------------------
extern "C" void kernel_launch(void* const* d_in, const int* in_sizes, int n_in,
                              void* d_out, int out_size, void* d_ws, size_t ws_size,
                              hipStream_t stream)
{
    const float* x     = (const float*)d_in[0];
    const float* gw    = (const float*)d_in[1];
    const float* gb    = (const float*)d_in[2];
    const float* tw    = (const float*)d_in[3];
    const float* tb    = (const float*)d_in[4];
    const float* pw    = (const float*)d_in[5];
    const float* pb    = (const float*)d_in[6];
    const float* ow    = (const float*)d_in[7];
    const float* ob    = (const float*)d_in[8];
    const float* gamma = (const float*)d_in[9];
    const float* beta  = (const float*)d_in[10];
    float* out = (float*)d_out;

    // workspace layout (bytes)
    char* wsb = (char*)d_ws;
    uint2* th_sw  = (uint2*)(wsb);                 // 512 KB
    uint2* phi_sw = (uint2*)(wsb + (512u<<10));    // 512 KB
    uint4* g_sw   = (uint4*)(wsb + (1024u<<10));   // 512 KB
    float* lp     = (float*)(wsb + (1536u<<10));   // 256 KB
    float* shst   = (float*)(wsb + (1792u<<10));   // 4 KB (8 shadows x 128)
    float* accp   = (float*)(wsb + (2048u<<10));   // 4 MB [4][4][4096][16]
    float* z      = (float*)(wsb + (6u<<20) + (256u<<10)); // 16.8 MB

    k_proj<<<256, 256, 0, stream>>>(x, gw, gb, tw, tb, pw, pb,
                                    th_sw, phi_sw, g_sw, shst);
    k_attn<<<dim3(64, KSPL, NB), 256, 0, stream>>>(th_sw, phi_sw, g_sw, accp, lp);
    k_outz<<<dim3(64, NB), 256, 0, stream>>>(accp, lp, x, ow, ob, z, shst);
    k_norm<<<1024, 256, 0, stream>>>(z, shst, gamma, beta, out);
}